// Round 6
// baseline (14842.068 us; speedup 1.0000x reference)
//
#include <hip/hip_runtime.h>

#define T_LEN 16384
#define NT 1024
#define NBLK 32      // blocks per direction (x2 directions)
#define CPB 32       // columns (fwd) / rows (bwd) per block
#define NTHR 256     // 4 waves
#define MID 8191     // fwd computes alpha_MID (8191 steps); bwd beta_MID (8192 steps)

typedef unsigned long long u64;
typedef unsigned int u32;
typedef __attribute__((ext_vector_type(4))) u32 u32x4;

// Exchange buffers (proven protocol): [0..NT) even-parity tags, [NT..2NT) odd.
// tagged word = (step_tag << 32) | float_bits; tag+data fused => no fences needed.
__device__ __align__(32) u64 g_fbuf[2 * NT];
__device__ __align__(32) u64 g_bbuf[2 * NT];

__device__ __forceinline__ u64 pack_tag(u32 tag, float v) {
  return ((u64)tag << 32) | (u64)__float_as_uint(v);
}
__device__ __forceinline__ u64 ld_tag(const u64* p) {
  return __hip_atomic_load(p, __ATOMIC_RELAXED, __HIP_MEMORY_SCOPE_AGENT);
}
__device__ __forceinline__ void st_tag(u64* p, u64 v) {
  __hip_atomic_store(p, v, __ATOMIC_RELAXED, __HIP_MEMORY_SCOPE_AGENT);
}

// Batched device-scope poll: 4 contiguous tagged words (32B) in 2 dwordx4 loads.
// sc0 (bypass L1) + sc1 (bypass L2) => coherent at MALL, same point as the
// agent-scope atomic path. Per-word tags validate each 8B word independently.
__device__ __forceinline__ void ld8_dev(const u64* q, u32x4& A, u32x4& B) {
  asm volatile("global_load_dwordx4 %0, %2, off sc0 sc1\n\t"
               "global_load_dwordx4 %1, %2, off offset:16 sc0 sc1\n\t"
               "s_waitcnt vmcnt(0)"
               : "=&v"(A), "=&v"(B)
               : "v"(q)
               : "memory");
}

__global__ __launch_bounds__(1024) void crf_init(const float* __restrict__ emit,
                                                 const float* __restrict__ strans,
                                                 const float* __restrict__ etrans) {
  int tid = threadIdx.x;
  g_fbuf[tid] = pack_tag(0u, strans[tid] + emit[tid]);
  g_bbuf[tid] = pack_tag(0u, etrans[tid] + emit[(T_LEN - 1) * NT + tid]);
}

__global__ __launch_bounds__(1024) void crf_score(const float* __restrict__ emit,
                                                  const int* __restrict__ y,
                                                  const float* __restrict__ trans,
                                                  const float* __restrict__ strans,
                                                  const float* __restrict__ etrans,
                                                  float* __restrict__ ws) {
  int tid = threadIdx.x;
  float local = 0.f;
  for (int t = tid; t < T_LEN; t += 1024) {
    int yt = y[t];
    local += emit[t * NT + yt];
    if (t > 0) local += trans[y[t - 1] * NT + yt];
  }
  if (tid == 0) local += strans[y[0]];
  if (tid == 1023) local += etrans[y[T_LEN - 1]];
#pragma unroll
  for (int o = 32; o; o >>= 1) local += __shfl_xor(local, o);
  __shared__ float sm[16];
  if ((tid & 63) == 0) sm[tid >> 6] = local;
  __syncthreads();
  if (tid == 0) {
    float s = 0.f;
    for (int i = 0; i < 16; ++i) s += sm[i];
    ws[4096] = s;
  }
}

// Blocks [0,32): forward chain. Blocks [32,64): backward chain.
// 32 cols/block halves the polling population vs R5 (the measured binding term).
// Per-step schedule is the verified R5 shape: batched poll -> fill -> barrier ->
// GEMV -> barrier -> combine -> single coalesced 256B store.
__global__ __launch_bounds__(NTHR, 1) void crf_scan(const float* __restrict__ emit,
                                                    const float* __restrict__ trans) {
  const int tid = threadIdx.x;
  const bool fwd = blockIdx.x < NBLK;
  const int blk = fwd ? blockIdx.x : (blockIdx.x - NBLK);

  const int c = tid & 31;        // local column (fwd) / row (bwd)
  const int chunk = tid >> 5;    // reduction-dim chunk 0..7 (128 each)
  const int col = blk * CPB + c;
  const int wv = tid >> 6;       // wave 0..3

  u64* buf0 = fwd ? g_fbuf : g_bbuf;
  u64* buf1 = buf0 + NT;
  const int STEPS = fwd ? MID : (T_LEN - 1 - MID);   // 8191 / 8192

  // P fragment: p[4i+x] = exp(trans[j, col]) (fwd) / exp(trans[col, j]) (bwd),
  // j = 128*chunk + ((4i + 8*chunk) & 127) + x.  Stagger keeps the distinct
  // float4 lines per wave-read on separate bank quads (2 lines/wave -> free).
  float p[128];
  const int jbase = chunk << 7;
#pragma unroll
  for (int i = 0; i < 32; ++i) {
    int off = (4 * i + 8 * chunk) & 127;
#pragma unroll
    for (int x = 0; x < 4; ++x) {
      int jj = jbase + off + x;
      float tv = fwd ? trans[jj * NT + col] : trans[col * NT + jj];
      p[4 * i + x] = __expf(tv);
    }
  }

  __shared__ __align__(16) float aS[NT];
  __shared__ float partS[4][32];   // [wave][col]

  // initial block-local scale M = max over this block's 32 seed values
  float M;
  {
    u64 wd = ld_tag(buf0 + col);
    float v = __uint_as_float((u32)wd);
#pragma unroll
    for (int o = 16; o; o >>= 1) v = fmaxf(v, __shfl_xor(v, o));
    M = v;
  }

  for (int n = 1; n <= STEPS; ++n) {
    u64* bIn  = (n & 1) ? buf0 : buf1;   // holds tag n-1
    u64* bOut = (n & 1) ? buf1 : buf0;   // receives tag n

    const int te = fwd ? n : (T_LEN - 1 - n);
    float e = emit[te * NT + col];       // issued before the poll; overlaps it

    // Batched poll: this thread's 4 contiguous words [4*tid, 4*tid+4).
    // The 4 words lie inside ONE producer's 32-word span -> arrive together.
    const u32 want = (u32)(n - 1);
    const u64* q = bIn + (tid << 2);
    u32x4 A, B;
    for (;;) {
      ld8_dev(q, A, B);
      if (!((A.y ^ want) | (A.w ^ want) | (B.y ^ want) | (B.w ^ want))) break;
    }
    float4 av;
    av.x = __expf(__uint_as_float(A.x) - M);
    av.y = __expf(__uint_as_float(A.z) - M);
    av.z = __expf(__uint_as_float(B.x) - M);
    av.w = __expf(__uint_as_float(B.z) - M);
    ((float4*)aS)[tid] = av;             // one contiguous ds_write_b128
    __syncthreads();

    // GEMV: thread owns (c, 128-wide chunk): 32 broadcast float4 reads + 128 FMA
    float s = 0.f;
    const float4* aV = (const float4*)aS;
#pragma unroll
    for (int i = 0; i < 32; ++i) {
      int off = (4 * i + 8 * chunk) & 127;
      float4 a4 = aV[(jbase + off) >> 2];
      s = fmaf(a4.x, p[4 * i + 0], s);
      s = fmaf(a4.y, p[4 * i + 1], s);
      s = fmaf(a4.z, p[4 * i + 2], s);
      s = fmaf(a4.w, p[4 * i + 3], s);
    }
    // combine the wave's 2 chunks (lane bit 5)
    s += __shfl_xor(s, 32);
    if ((tid & 63) < 32) partS[wv][c] = s;
    __syncthreads();

    // final cross-wave combine, done redundantly by every thread (4 LDS reads)
    float tot = partS[0][c] + partS[1][c] + partS[2][c] + partS[3][c];
    float anew = e + M + __logf(tot);
    // single coalesced 256B store from one wave (do not fragment — R4 lesson)
    if (tid < 32) st_tag(bOut + col, pack_tag((u32)n, anew));

    // block-local M for next step: max over this block's 32 fresh values
    float m2 = anew;
#pragma unroll
    for (int o = 16; o; o >>= 1) m2 = fmaxf(m2, __shfl_xor(m2, o));
    M = m2;
  }
}

__global__ __launch_bounds__(1024) void crf_final(const float* __restrict__ emit,
                                                  const float* __restrict__ ws,
                                                  float* __restrict__ out) {
  int tid = threadIdx.x;
  // alpha_MID: tag 8191 (odd) -> g_fbuf odd half.
  // beta-stream tag 8192 (even) -> g_bbuf even half; stored = beta_MID + emit[MID,:].
  float fa = __uint_as_float((u32)g_fbuf[NT + tid]);
  float bb = __uint_as_float((u32)g_bbuf[tid]);
  float v = fa + bb - emit[MID * NT + tid];   // alpha_MID + beta_MID
  float m = v;
#pragma unroll
  for (int o = 32; o; o >>= 1) m = fmaxf(m, __shfl_xor(m, o));
  __shared__ float sm[16];
  __shared__ float sM;
  if ((tid & 63) == 0) sm[tid >> 6] = m;
  __syncthreads();
  if (tid == 0) {
    float mm = sm[0];
    for (int i = 1; i < 16; ++i) mm = fmaxf(mm, sm[i]);
    sM = mm;
  }
  __syncthreads();
  float Mv = sM;
  float s = __expf(v - Mv);
#pragma unroll
  for (int o = 32; o; o >>= 1) s += __shfl_xor(s, o);
  __shared__ float ss[16];
  if ((tid & 63) == 0) ss[tid >> 6] = s;
  __syncthreads();
  if (tid == 0) {
    float tot = 0.f;
    for (int i = 0; i < 16; ++i) tot += ss[i];
    float logZ = Mv + __logf(tot);
    out[0] = logZ - ws[4096];
  }
}

extern "C" void kernel_launch(void* const* d_in, const int* in_sizes, int n_in,
                              void* d_out, int out_size, void* d_ws, size_t ws_size,
                              hipStream_t stream) {
  const float* emit = (const float*)d_in[0];
  const int* y = (const int*)d_in[1];
  const float* trans = (const float*)d_in[2];
  const float* strans = (const float*)d_in[3];
  const float* etrans = (const float*)d_in[4];
  float* ws = (float*)d_ws;
  float* out = (float*)d_out;

  crf_init<<<1, 1024, 0, stream>>>(emit, strans, etrans);
  crf_score<<<1, 1024, 0, stream>>>(emit, y, trans, strans, etrans, ws);
  crf_scan<<<2 * NBLK, NTHR, 0, stream>>>(emit, trans);
  crf_final<<<1, 1024, 0, stream>>>(emit, ws, out);
}

// Round 7
// 13383.012 us; speedup vs baseline: 1.1090x; 1.1090x over previous
//
#include <hip/hip_runtime.h>

#define T_LEN 16384
#define NT 1024
#define NBLK 64      // blocks per direction (x2 directions)
#define CPB 16       // columns (fwd) / rows (bwd) per block
#define NTHR 256     // 4 waves
#define MID 8191     // fwd computes alpha_MID (8191 steps); bwd beta_MID (8192 steps)

typedef unsigned long long u64;
typedef unsigned int u32;
typedef __attribute__((ext_vector_type(4))) u32 u32x4;

// Exchange buffers (proven protocol): [0..NT) even-parity tags, [NT..2NT) odd.
// tagged word = (step_tag << 32) | float_bits; tag+data fused => no fences needed.
__device__ __align__(32) u64 g_fbuf[2 * NT];
__device__ __align__(32) u64 g_bbuf[2 * NT];

__device__ __forceinline__ u64 pack_tag(u32 tag, float v) {
  return ((u64)tag << 32) | (u64)__float_as_uint(v);
}
__device__ __forceinline__ u64 ld_tag(const u64* p) {
  return __hip_atomic_load(p, __ATOMIC_RELAXED, __HIP_MEMORY_SCOPE_AGENT);
}
__device__ __forceinline__ void st_tag(u64* p, u64 v) {
  __hip_atomic_store(p, v, __ATOMIC_RELAXED, __HIP_MEMORY_SCOPE_AGENT);
}

// ---- depth-2 pipelined device-scope poll (counted vmcnt, T4 pattern) ----
// Issue 4 contiguous tagged words (32B) as 2 dwordx4, WITHOUT waiting.
__device__ __forceinline__ void ld8_issue(const u64* q, u32x4& A, u32x4& B) {
  asm volatile("global_load_dwordx4 %0, %2, off sc0 sc1\n\t"
               "global_load_dwordx4 %1, %2, off offset:16 sc0 sc1"
               : "=&v"(A), "=&v"(B)
               : "v"(q)
               : "memory");
}
// Wait until at most 2 VMEM ops outstanding => everything except the newest
// pair has landed (in particular the pair A,B we are about to check).
// "+v" pins the checked pair's registers live across the wait; sched_barrier
// stops the compiler hoisting consumers above the wait (rule #18).
__device__ __forceinline__ void vm_wait2(u32x4& A, u32x4& B) {
  asm volatile("s_waitcnt vmcnt(2)" : "+v"(A), "+v"(B));
  __builtin_amdgcn_sched_barrier(0);
}
__device__ __forceinline__ void vm_wait0() {
  asm volatile("s_waitcnt vmcnt(0)" ::: "memory");
  __builtin_amdgcn_sched_barrier(0);
}

__global__ __launch_bounds__(1024) void crf_init(const float* __restrict__ emit,
                                                 const float* __restrict__ strans,
                                                 const float* __restrict__ etrans) {
  int tid = threadIdx.x;
  g_fbuf[tid] = pack_tag(0u, strans[tid] + emit[tid]);
  g_bbuf[tid] = pack_tag(0u, etrans[tid] + emit[(T_LEN - 1) * NT + tid]);
}

__global__ __launch_bounds__(1024) void crf_score(const float* __restrict__ emit,
                                                  const int* __restrict__ y,
                                                  const float* __restrict__ trans,
                                                  const float* __restrict__ strans,
                                                  const float* __restrict__ etrans,
                                                  float* __restrict__ ws) {
  int tid = threadIdx.x;
  float local = 0.f;
  for (int t = tid; t < T_LEN; t += 1024) {
    int yt = y[t];
    local += emit[t * NT + yt];
    if (t > 0) local += trans[y[t - 1] * NT + yt];
  }
  if (tid == 0) local += strans[y[0]];
  if (tid == 1023) local += etrans[y[T_LEN - 1]];
#pragma unroll
  for (int o = 32; o; o >>= 1) local += __shfl_xor(local, o);
  __shared__ float sm[16];
  if ((tid & 63) == 0) sm[tid >> 6] = local;
  __syncthreads();
  if (tid == 0) {
    float s = 0.f;
    for (int i = 0; i < 16; ++i) s += sm[i];
    ws[4096] = s;
  }
}

// Blocks [0,64): forward chain. Blocks [64,128): backward chain.
// R5 structure (CPB=16, batched poll, single coalesced 128B store) plus:
//  (a) depth-2 pipelined poll — detect quantization ~halved;
//  (b) no fill->GEMV barrier — wave w fills and reads exactly aS[256w,256w+256)
//      (wave-private RAW, in-order per-wave LDS pipe), so early waves run ahead.
__global__ __launch_bounds__(NTHR, 1) void crf_scan(const float* __restrict__ emit,
                                                    const float* __restrict__ trans) {
  const int tid = threadIdx.x;
  const bool fwd = blockIdx.x < NBLK;
  const int blk = fwd ? blockIdx.x : (blockIdx.x - NBLK);

  const int c = tid & 15;        // local column (fwd) / row (bwd)
  const int chunk = tid >> 4;    // reduction-dim chunk 0..15 (64 each)
  const int col = blk * CPB + c;
  const int wv = tid >> 6;       // wave 0..3

  u64* buf0 = fwd ? g_fbuf : g_bbuf;
  u64* buf1 = buf0 + NT;
  const int STEPS = fwd ? MID : (T_LEN - 1 - MID);   // 8191 / 8192

  // P fragment: fwd: p = exp(trans[j, col]); bwd: p = exp(trans[col, j]).
  // 8*chunk stagger keeps the 4 distinct LDS lines per wave-read on disjoint
  // bank quads -> conflict-free broadcast reads (unchanged).
  float p[64];
  const int jbase = chunk * 64;
#pragma unroll
  for (int i = 0; i < 16; ++i) {
    int off = (4 * i + 8 * chunk) & 63;
#pragma unroll
    for (int x = 0; x < 4; ++x) {
      int jj = jbase + off + x;
      float tv = fwd ? trans[jj * NT + col] : trans[col * NT + jj];
      p[4 * i + x] = __expf(tv);
    }
  }

  __shared__ __align__(16) float aS[NT];
  __shared__ float partS[64];    // [wave][16 cols]

  // initial block-local scale M = max over this block's 16 seed values
  float M;
  {
    u64 wd = ld_tag(buf0 + col);
    float v = __uint_as_float((u32)wd);
#pragma unroll
    for (int o = 8; o; o >>= 1) v = fmaxf(v, __shfl_xor(v, o));
    M = v;
  }

  for (int n = 1; n <= STEPS; ++n) {
    u64* bIn  = (n & 1) ? buf0 : buf1;   // holds tag n-1
    u64* bOut = (n & 1) ? buf1 : buf0;   // receives tag n

    const int te = fwd ? n : (T_LEN - 1 - n);
    float e = emit[te * NT + col];       // in flight; used after the poll drain

    // ---- depth-2 pipelined poll on [4*tid, 4*tid+4) ----
    const u32 want = (u32)(n - 1);
    const u64* q = bIn + (tid << 2);
    u32x4 A0, B0, A1, B1;
    ld8_issue(q, A0, B0);
    ld8_issue(q, A1, B1);
    float4 av;
    for (;;) {
      vm_wait2(A0, B0);                  // pair0 landed (pair1 still flying)
      if (!((A0.y ^ want) | (A0.w ^ want) | (B0.y ^ want) | (B0.w ^ want))) {
        av.x = __uint_as_float(A0.x); av.y = __uint_as_float(A0.z);
        av.z = __uint_as_float(B0.x); av.w = __uint_as_float(B0.z);
        break;
      }
      ld8_issue(q, A0, B0);              // refill slot 0
      vm_wait2(A1, B1);                  // pair1 landed (pair0 still flying)
      if (!((A1.y ^ want) | (A1.w ^ want) | (B1.y ^ want) | (B1.w ^ want))) {
        av.x = __uint_as_float(A1.x); av.y = __uint_as_float(A1.z);
        av.z = __uint_as_float(B1.x); av.w = __uint_as_float(B1.z);
        break;
      }
      ld8_issue(q, A1, B1);              // refill slot 1
    }
    vm_wait0();                          // drain the still-flying pair before
                                         // its registers are reused next iter
    av.x = __expf(av.x - M);
    av.y = __expf(av.y - M);
    av.z = __expf(av.z - M);
    av.w = __expf(av.w - M);
    ((float4*)aS)[tid] = av;             // one contiguous ds_write_b128

    // NO barrier: wave w wrote aS[256w..256w+256) and reads only that range.

    // GEMV: thread owns (c, chunk): 16 broadcast float4 reads, 2 acc chains
    float s0 = 0.f, s1 = 0.f;
    const float4* aV = (const float4*)aS;
#pragma unroll
    for (int i = 0; i < 16; i += 2) {
      int offA = (4 * i + 8 * chunk) & 63;
      int offB = (4 * i + 4 + 8 * chunk) & 63;
      float4 a4 = aV[(jbase + offA) >> 2];
      float4 b4 = aV[(jbase + offB) >> 2];
      s0 = fmaf(a4.x, p[4 * i + 0], s0);
      s0 = fmaf(a4.y, p[4 * i + 1], s0);
      s0 = fmaf(a4.z, p[4 * i + 2], s0);
      s0 = fmaf(a4.w, p[4 * i + 3], s0);
      s1 = fmaf(b4.x, p[4 * i + 4], s1);
      s1 = fmaf(b4.y, p[4 * i + 5], s1);
      s1 = fmaf(b4.z, p[4 * i + 6], s1);
      s1 = fmaf(b4.w, p[4 * i + 7], s1);
    }
    float s = s0 + s1;
    // reduce over the wave's 4 chunks (tid bits 4,5)
    s += __shfl_xor(s, 16);
    s += __shfl_xor(s, 32);
    if ((tid & 63) < 16) partS[wv * 16 + c] = s;
    __syncthreads();                     // the one cross-wave sync per step

    // final cross-wave combine, done redundantly by every thread (4 LDS reads)
    float tot = partS[c] + partS[16 + c] + partS[32 + c] + partS[48 + c];
    float anew = e + M + __logf(tot);
    // single coalesced 128B store from one wave (do not fragment — R4 lesson)
    if (tid < 16) st_tag(bOut + col, pack_tag((u32)n, anew));

    // block-local M for next step: max over this block's 16 fresh values
    float m2 = anew;
#pragma unroll
    for (int o = 8; o; o >>= 1) m2 = fmaxf(m2, __shfl_xor(m2, o));
    M = m2;
  }
}

__global__ __launch_bounds__(1024) void crf_final(const float* __restrict__ emit,
                                                  const float* __restrict__ ws,
                                                  float* __restrict__ out) {
  int tid = threadIdx.x;
  // alpha_MID: tag 8191 (odd) -> g_fbuf odd half.
  // beta-stream tag 8192 (even) -> g_bbuf even half; stored = beta_MID + emit[MID,:].
  float fa = __uint_as_float((u32)g_fbuf[NT + tid]);
  float bb = __uint_as_float((u32)g_bbuf[tid]);
  float v = fa + bb - emit[MID * NT + tid];   // alpha_MID + beta_MID
  float m = v;
#pragma unroll
  for (int o = 32; o; o >>= 1) m = fmaxf(m, __shfl_xor(m, o));
  __shared__ float sm[16];
  __shared__ float sM;
  if ((tid & 63) == 0) sm[tid >> 6] = m;
  __syncthreads();
  if (tid == 0) {
    float mm = sm[0];
    for (int i = 1; i < 16; ++i) mm = fmaxf(mm, sm[i]);
    sM = mm;
  }
  __syncthreads();
  float Mv = sM;
  float s = __expf(v - Mv);
#pragma unroll
  for (int o = 32; o; o >>= 1) s += __shfl_xor(s, o);
  __shared__ float ss[16];
  if ((tid & 63) == 0) ss[tid >> 6] = s;
  __syncthreads();
  if (tid == 0) {
    float tot = 0.f;
    for (int i = 0; i < 16; ++i) tot += ss[i];
    float logZ = Mv + __logf(tot);
    out[0] = logZ - ws[4096];
  }
}

extern "C" void kernel_launch(void* const* d_in, const int* in_sizes, int n_in,
                              void* d_out, int out_size, void* d_ws, size_t ws_size,
                              hipStream_t stream) {
  const float* emit = (const float*)d_in[0];
  const int* y = (const int*)d_in[1];
  const float* trans = (const float*)d_in[2];
  const float* strans = (const float*)d_in[3];
  const float* etrans = (const float*)d_in[4];
  float* ws = (float*)d_ws;
  float* out = (float*)d_out;

  crf_init<<<1, 1024, 0, stream>>>(emit, strans, etrans);
  crf_score<<<1, 1024, 0, stream>>>(emit, y, trans, strans, etrans, ws);
  crf_scan<<<2 * NBLK, NTHR, 0, stream>>>(emit, trans);
  crf_final<<<1, 1024, 0, stream>>>(emit, ws, out);
}